// Round 10
// baseline (116.753 us; speedup 1.0000x reference)
//
#include <hip/hip_runtime.h>
#include <math.h>

#define DIM 1024
#define NH 16
#define NKV 4
#define HD 64
#define HALF 32
#define NB 2
#define SEQ 2048
#define KVD 256         // NKV*HD
#define MTOT 4096       // NB*SEQ
#define QSCALE 0.18033688f   // 0.125 * log2(e): softmax runs in exp2 domain
#define MBIAS 8.0f           // static softmax bias (S sd ~0.6; overflow-safe by >100 binades)

typedef __bf16 bf16x8 __attribute__((ext_vector_type(8)));
typedef float f32x4 __attribute__((ext_vector_type(4)));
typedef unsigned short u16x8 __attribute__((ext_vector_type(8)));

#define MFMA16(a, b, c) __builtin_amdgcn_mfma_f32_16x16x32_bf16(a, b, c, 0, 0, 0)

__device__ __forceinline__ unsigned short f2bf(float f) {
    unsigned int u = __float_as_uint(f);
    u = (u + 0x7fffu + ((u >> 16) & 1u)) >> 16;
    return (unsigned short)u;
}

// packed f32x2 -> bf16x2 (RNE), single HW instruction
__device__ __forceinline__ unsigned cvt_pk(float lo, float hi) {
    unsigned r;
    asm("v_cvt_pk_bf16_f32 %0, %1, %2" : "=v"(r) : "v"(lo), "v"(hi));
    return r;
}

// async 16B global->LDS: LDS dest = wave-uniform base + lane*16
__device__ __forceinline__ void gll16(const unsigned short* g, unsigned short* l) {
    __builtin_amdgcn_global_load_lds((const __attribute__((address_space(1))) void*)g,
                                     (__attribute__((address_space(3))) void*)l, 16, 0, 0);
}

// ---------------- merged prep: rope table + x->bf16 + weight transpose ----------------
__global__ __launch_bounds__(256) void prep_kernel(
    const float* __restrict__ x,
    const float* __restrict__ Wq, const float* __restrict__ Wk,
    const float* __restrict__ Wv, const float* __restrict__ Wo,
    unsigned short* __restrict__ xb,
    unsigned short* __restrict__ qt, unsigned short* __restrict__ kt,
    unsigned short* __restrict__ vt, unsigned short* __restrict__ ot,
    float* __restrict__ cosb, float* __restrict__ sinb)
{
    __shared__ float tile[64][65];
    const int bx = blockIdx.x;
    const int tid = threadIdx.x;
    if (bx < 256) {
        int idx = bx * 256 + tid;         // 64K entries
        int t = idx >> 5, d = idx & 31;
        float e = (float)(2 * d) / (float)HD;
        float invf = 1.0f / powf(10000.0f, e);
        float f = (float)t * invf;
        cosb[idx] = cosf(f);
        sinb[idx] = sinf(f);
    } else if (bx < 2304) {
        int i = ((bx - 256) * 256 + tid) * 8;
        float4 v0 = *(const float4*)&x[i];
        float4 v1 = *(const float4*)&x[i + 4];
        u16x8 o;
        o[0] = f2bf(v0.x); o[1] = f2bf(v0.y); o[2] = f2bf(v0.z); o[3] = f2bf(v0.w);
        o[4] = f2bf(v1.x); o[5] = f2bf(v1.y); o[6] = f2bf(v1.z); o[7] = f2bf(v1.w);
        *(u16x8*)&xb[i] = o;
    } else {
        int idx2 = bx - 2304;             // 1024 blocks: 4 matrices x 16x16 tiles
        int z = idx2 >> 8, rem = idx2 & 255, xx = rem & 15, yy = rem >> 4;
        const float* W; unsigned short* Wt; int N;
        switch (z) {
            case 0: W = Wq; Wt = qt; N = DIM; break;
            case 1: W = Wk; Wt = kt; N = KVD; break;
            case 2: W = Wv; Wt = vt; N = KVD; break;
            default: W = Wo; Wt = ot; N = DIM; break;
        }
        const int n0 = xx * 64;
        if (n0 >= N) return;
        const int k0 = yy * 64;
        const int row = tid >> 2, coff = (tid & 3) * 16;
#pragma unroll
        for (int i = 0; i < 4; i++) {
            float4 v = *(const float4*)&W[(size_t)(k0 + row) * N + n0 + coff + i * 4];
            tile[row][coff + i * 4 + 0] = v.x; tile[row][coff + i * 4 + 1] = v.y;
            tile[row][coff + i * 4 + 2] = v.z; tile[row][coff + i * 4 + 3] = v.w;
        }
        __syncthreads();
        u16x8 a, b;
#pragma unroll
        for (int i = 0; i < 8; i++) a[i] = f2bf(tile[coff + i][row]);
#pragma unroll
        for (int i = 0; i < 8; i++) b[i] = f2bf(tile[coff + 8 + i][row]);
        *(u16x8*)&Wt[(size_t)(n0 + row) * DIM + k0 + coff] = a;
        *(u16x8*)&Wt[(size_t)(n0 + row) * DIM + k0 + coff + 8] = b;
    }
}

// ---------------- fused QKV GEMM + bias + RoPE; V written transposed ----------------
// 64x128 tile (M x N), 4 waves 2x2 (wave tile 32x64); 768 blocks = 3/CU
__global__ __launch_bounds__(256) void qkv_gemm_kernel(
    const unsigned short* __restrict__ xb,
    const unsigned short* __restrict__ wqt, const unsigned short* __restrict__ wkt,
    const unsigned short* __restrict__ wvt,
    const float* __restrict__ bq, const float* __restrict__ bk, const float* __restrict__ bv,
    const float* __restrict__ cosb, const float* __restrict__ sinb,
    unsigned short* __restrict__ qbuf, unsigned short* __restrict__ kbuf,
    unsigned short* __restrict__ vT)
{
    __shared__ unsigned short As[64 * 32];
    __shared__ unsigned short Bs[128 * 32];
    const int tid = threadIdx.x;
    const int lane = tid & 63, w = tid >> 6;
    const int l15 = lane & 15, lg = lane >> 4;
    const int bid = blockIdx.x;                 // 768 blocks
    const int lid = (bid & 7) * 96 + (bid >> 3);
    const int m0 = (lid / 12) * 64;
    const int n0g = (lid % 12) * 128;

    const unsigned short* Wt; const float* bias; int n0, mode;
    if (n0g < DIM)            { Wt = wqt; bias = bq; n0 = n0g; mode = 0; }
    else if (n0g < DIM + KVD) { Wt = wkt; bias = bk; n0 = n0g - DIM; mode = 1; }
    else                      { Wt = wvt; bias = bv; n0 = n0g - DIM - KVD; mode = 2; }

    const int wr = w >> 1, wc = w & 1;          // wave tile 32x64 at (wr*32, wc*64)
    const int Ar = tid >> 2, Ac8 = (tid & 3) * 8;

    f32x4 acc[2][4];
#pragma unroll
    for (int i = 0; i < 2; i++)
#pragma unroll
        for (int j = 0; j < 4; j++) acc[i][j] = (f32x4){0.f, 0.f, 0.f, 0.f};

    for (int k0 = 0; k0 < DIM; k0 += 32) {
        __syncthreads();
        gll16(xb + (size_t)(m0 + Ar) * DIM + k0 + Ac8, &As[(tid & ~63) * 8]);
#pragma unroll
        for (int i = 0; i < 2; i++) {
            int S = i * 256 + tid;
            int r = S >> 2, c8 = (S & 3) * 8;
            gll16(Wt + (size_t)(n0 + r) * DIM + k0 + c8, &Bs[(i * 256 + (tid & ~63)) * 8]);
        }
        __syncthreads();
        bf16x8 af[2], bfr[4];
#pragma unroll
        for (int r = 0; r < 2; r++)
            af[r] = *(const bf16x8*)&As[(wr * 32 + r * 16 + l15) * 32 + lg * 8];
#pragma unroll
        for (int c = 0; c < 4; c++)
            bfr[c] = *(const bf16x8*)&Bs[(wc * 64 + c * 16 + l15) * 32 + lg * 8];
#pragma unroll
        for (int r = 0; r < 2; r++)
#pragma unroll
            for (int c = 0; c < 4; c++)
                acc[r][c] = MFMA16(af[r], bfr[c], acc[r][c]);
    }

    const int nloc = n0 + wc * 64;
    const bool even = (l15 & 1) == 0;
#pragma unroll
    for (int rt = 0; rt < 2; rt++) {
#pragma unroll
        for (int ct = 0; ct < 4; ct++) {
            const int c = ct * 16 + l15;
            const float bsv = bias[nloc + c];
            if (mode == 2) {
                const int col = nloc + c;               // 0..255
                const int khh = col >> 6, d = col & 63;
                const int bb = m0 >> 11;
                const int t = (m0 & (SEQ - 1)) + wr * 32 + rt * 16 + lg * 4;
                float v0 = acc[rt][ct][0] + bsv;
                float v1 = acc[rt][ct][1] + bsv;
                float v2 = acc[rt][ct][2] + bsv;
                float v3 = acc[rt][ct][3] + bsv;
                unsigned short* dst = vT + ((size_t)(bb * NKV + khh) * 64 + d) * SEQ + t;
                *(uint2*)dst = make_uint2(cvt_pk(v0, v1), cvt_pk(v2, v3));
            } else {
                const int p = c >> 1;
#pragma unroll
                for (int q = 0; q < 4; q++) {
                    const int mrow = m0 + wr * 32 + rt * 16 + lg * 4 + q;
                    float val = acc[rt][ct][q] + bsv;
                    float prt = __shfl_xor(val, 1);
                    const int t = mrow & (SEQ - 1);
                    float cs = cosb[t * HALF + p];
                    float sn = sinb[t * HALF + p];
                    float outv = even ? (val * cs - prt * sn) : (prt * sn - val * cs);
                    int outc = even ? p : (p + 32);
                    if (mode == 0) qbuf[(size_t)mrow * DIM + nloc + outc] = f2bf(outv * QSCALE);
                    else           kbuf[(size_t)mrow * KVD + nloc + outc] = f2bf(outv);
                }
            }
        }
    }
}

// ---------------- flash attention: 2 waves x 32 q-rows, shared K/V frags, dbuf ----------------
// softmax: STATIC bias P = exp2(S - 8); ratios exact, overflow-safe
__global__ __launch_bounds__(128, 2) void attn_mfma_kernel(
    const unsigned short* __restrict__ qb, const unsigned short* __restrict__ kb,
    const unsigned short* __restrict__ vT, unsigned short* __restrict__ ctx)
{
    __shared__ unsigned short Ks[2][64 * 64];   // [key][d], XOR-swizzled, double-buffered
    __shared__ unsigned short Vt[2][64 * 64];   // [d][j], j swizzled by (d&7)<<3
    __shared__ unsigned Pw[2][2][16 * 32];      // [wave][qset] P rows  (total LDS = 40 KB)

    const int tid = threadIdx.x;
    const int lane = tid & 63, w = tid >> 6;    // 2 waves
    const int l15 = lane & 15, lg = lane >> 4;
    const int h = blockIdx.y;
    const int b = blockIdx.z;
    const int kh = h >> 2;
    // tile swizzle: a CU's 4 blocks differ in g by 8 -> tiles spread {t,t+8,t+16,t+24}
    const int g = h + NH * b;                   // 0..31
    const int tile = (blockIdx.x + g) & 31;
    const int q0 = tile * 64;

    const unsigned short* kg = kb + (size_t)b * SEQ * KVD + (size_t)kh * HD;
    const unsigned short* vg = vT + ((size_t)(b * NKV + kh) * HD) * SEQ;

    const int swzd = (l15 & 7) << 3;
    const int pswz = (l15 & 7) << 2;
    unsigned* PW0 = &Pw[w][0][l15 * 32];
    unsigned* PW1 = &Pw[w][1][l15 * 32];

    // ---- Q fragments for both q-sets, direct from global (once per block) ----
    bf16x8 bq[2][2];
#pragma unroll
    for (int s2 = 0; s2 < 2; s2++) {
        const unsigned short* qptr = qb +
            ((size_t)(b * SEQ + q0 + w * 32 + s2 * 16 + l15) * DIM + h * HD + lg * 8);
        bq[s2][0] = *(const bf16x8*)qptr;
        bq[s2][1] = *(const bf16x8*)(qptr + 32);
    }

    // staging geometry: 512 slots/buffer over 128 threads -> 4 slots each
    // slot S: row r = S>>3, quad qd = S&7, swizzled col d8
#define STAGE(bufK, bufV, kvoff)                                                   \
    _Pragma("unroll")                                                              \
    for (int i = 0; i < 4; i++) {                                                  \
        int S = i * 128 + tid;                                                     \
        int r = S >> 3, qd = S & 7;                                                \
        int d8 = ((qd ^ (r & 7))) * 8;                                             \
        gll16(kg + (size_t)((kvoff) + r) * KVD + d8, &(bufK)[(i * 128 + (tid & ~63)) * 8]); \
        gll16(vg + (size_t)r * SEQ + (kvoff) + d8,   &(bufV)[(i * 128 + (tid & ~63)) * 8]); \
    }

    // ---- prologue: stage chunk 0 into buf 0 ----
    STAGE(Ks[0], Vt[0], 0)
    __syncthreads();

    f32x4 o[2][4];
#pragma unroll
    for (int s2 = 0; s2 < 2; s2++)
#pragma unroll
        for (int i = 0; i < 4; i++) o[s2][i] = (f32x4){0.f, 0.f, 0.f, 0.f};
    float lrun0 = 0.f, lrun1 = 0.f;

    const int nch = tile + 1;
#pragma unroll 1
    for (int ch = 0; ch < nch; ch++) {
        const int cur = ch & 1;
        if (ch + 1 < nch) {
            const int kv1 = (ch + 1) * 64;
            STAGE(Ks[cur ^ 1], Vt[cur ^ 1], kv1)
        }

        // ---- S^T = K Q^T for both q-sets (K frag loaded once, used twice) ----
        f32x4 sacc[2][4];
#pragma unroll
        for (int s2 = 0; s2 < 2; s2++)
#pragma unroll
            for (int i = 0; i < 4; i++) sacc[s2][i] = (f32x4){0.f, 0.f, 0.f, 0.f};
        __builtin_amdgcn_s_setprio(1);
#pragma unroll
        for (int s = 0; s < 2; s++) {
#pragma unroll
            for (int ct = 0; ct < 4; ct++) {
                const int kr = ct * 16 + l15;
                bf16x8 ak = *(const bf16x8*)&Ks[cur][kr * 64 + ((s * 32 + lg * 8) ^ swzd)];
                sacc[0][ct] = MFMA16(ak, bq[0][s], sacc[0][ct]);
                sacc[1][ct] = MFMA16(ak, bq[1][s], sacc[1][ct]);
            }
        }
        __builtin_amdgcn_s_setprio(0);

        // ---- causal mask (diagonal chunk only) ----
        if (ch == nch - 1) {
#pragma unroll
            for (int s2 = 0; s2 < 2; s2++) {
                const int ql = w * 32 + s2 * 16 + l15;
#pragma unroll
                for (int ct = 0; ct < 4; ct++)
#pragma unroll
                    for (int r = 0; r < 4; r++)
                        if (ct * 16 + lg * 4 + r > ql) sacc[s2][ct][r] = -INFINITY;
            }
        }

        // ---- P = exp2(S - MBIAS), per-lane row-sum, pack, store to strips ----
#pragma unroll
        for (int ct = 0; ct < 4; ct++) {
            float a0 = exp2f(sacc[0][ct][0] - MBIAS);
            float a1 = exp2f(sacc[0][ct][1] - MBIAS);
            float a2 = exp2f(sacc[0][ct][2] - MBIAS);
            float a3 = exp2f(sacc[0][ct][3] - MBIAS);
            lrun0 += (a0 + a1) + (a2 + a3);
            int wrd = (ct * 8 + lg * 2) ^ pswz;
            *(uint2*)&PW0[wrd] = make_uint2(cvt_pk(a0, a1), cvt_pk(a2, a3));
            float b0 = exp2f(sacc[1][ct][0] - MBIAS);
            float b1 = exp2f(sacc[1][ct][1] - MBIAS);
            float b2 = exp2f(sacc[1][ct][2] - MBIAS);
            float b3 = exp2f(sacc[1][ct][3] - MBIAS);
            lrun1 += (b0 + b1) + (b2 + b3);
            *(uint2*)&PW1[wrd] = make_uint2(cvt_pk(b0, b1), cvt_pk(b2, b3));
        }

        // ---- O += P V (V frag loaded once, used twice) ----
        __builtin_amdgcn_s_setprio(1);
#pragma unroll
        for (int s = 0; s < 2; s++) {
            int wrd = (s * 16 + lg * 4) ^ pswz;
            bf16x8 ap0 = *(const bf16x8*)&PW0[wrd];
            bf16x8 ap1 = *(const bf16x8*)&PW1[wrd];
#pragma unroll
            for (int dt = 0; dt < 4; dt++) {
                const int d = dt * 16 + l15;
                bf16x8 bv2 = *(const bf16x8*)&Vt[cur][d * 64 + ((s * 32 + lg * 8) ^ ((d & 7) << 3))];
                o[0][dt] = MFMA16(ap0, bv2, o[0][dt]);
                o[1][dt] = MFMA16(ap1, bv2, o[1][dt]);
            }
        }
        __builtin_amdgcn_s_setprio(0);

        __syncthreads();   // drains staging loads; protects buffer swap
    }

    // ---- epilogue: reduce row-sums, normalize, write ctx ----
    lrun0 += __shfl_xor(lrun0, 16);
    lrun0 += __shfl_xor(lrun0, 32);
    lrun1 += __shfl_xor(lrun1, 16);
    lrun1 += __shfl_xor(lrun1, 32);
    float li0 = 1.0f / lrun0, li1 = 1.0f / lrun1;
#pragma unroll
    for (int s2 = 0; s2 < 2; s2++) {
        float li = (s2 == 0) ? li0 : li1;
        float lb0 = __shfl(li, lg * 4 + 0);
        float lb1 = __shfl(li, lg * 4 + 1);
        float lb2 = __shfl(li, lg * 4 + 2);
        float lb3 = __shfl(li, lg * 4 + 3);
#pragma unroll
        for (int dt = 0; dt < 4; dt++) {
            const size_t base = (size_t)(b * SEQ + q0 + w * 32 + s2 * 16 + lg * 4) * DIM
                                + h * HD + dt * 16 + l15;
            ctx[base]           = f2bf(o[s2][dt][0] * lb0);
            ctx[base + DIM]     = f2bf(o[s2][dt][1] * lb1);
            ctx[base + 2 * DIM] = f2bf(o[s2][dt][2] * lb2);
            ctx[base + 3 * DIM] = f2bf(o[s2][dt][3] * lb3);
        }
    }
}

// ---------------- out projection: 64x128 tile, 512 blocks = 2/CU ----------------
__global__ __launch_bounds__(256) void outproj_kernel(
    const unsigned short* __restrict__ ctx, const unsigned short* __restrict__ wot,
    const float* __restrict__ bo, float* __restrict__ out)
{
    __shared__ unsigned short As[64 * 32];
    __shared__ unsigned short Bs[128 * 32];
    const int tid = threadIdx.x;
    const int lane = tid & 63, w = tid >> 6;
    const int l15 = lane & 15, lg = lane >> 4;
    const int bid = blockIdx.x;                 // 512 blocks
    const int lid = (bid & 7) * 64 + (bid >> 3);
    const int m0 = (lid >> 3) * 64;
    const int n0 = (lid & 7) * 128;
    const int wr = w >> 1, wc = w & 1;
    const int Ar = tid >> 2, Ac8 = (tid & 3) * 8;

    f32x4 acc[2][4];
#pragma unroll
    for (int i = 0; i < 2; i++)
#pragma unroll
        for (int j = 0; j < 4; j++) acc[i][j] = (f32x4){0.f, 0.f, 0.f, 0.f};

    for (int k0 = 0; k0 < DIM; k0 += 32) {
        __syncthreads();
        gll16(ctx + (size_t)(m0 + Ar) * DIM + k0 + Ac8, &As[(tid & ~63) * 8]);
#pragma unroll
        for (int i = 0; i < 2; i++) {
            int S = i * 256 + tid;
            int r = S >> 2, c8 = (S & 3) * 8;
            gll16(wot + (size_t)(n0 + r) * DIM + k0 + c8, &Bs[(i * 256 + (tid & ~63)) * 8]);
        }
        __syncthreads();
        bf16x8 af[2], bfr[4];
#pragma unroll
        for (int r = 0; r < 2; r++)
            af[r] = *(const bf16x8*)&As[(wr * 32 + r * 16 + l15) * 32 + lg * 8];
#pragma unroll
        for (int c = 0; c < 4; c++)
            bfr[c] = *(const bf16x8*)&Bs[(wc * 64 + c * 16 + l15) * 32 + lg * 8];
#pragma unroll
        for (int r = 0; r < 2; r++)
#pragma unroll
            for (int c = 0; c < 4; c++)
                acc[r][c] = MFMA16(af[r], bfr[c], acc[r][c]);
    }

#pragma unroll
    for (int rt = 0; rt < 2; rt++) {
#pragma unroll
        for (int ct = 0; ct < 4; ct++) {
            const int ncol = n0 + wc * 64 + ct * 16 + l15;
            const float bsv = bo[ncol];
#pragma unroll
            for (int q = 0; q < 4; q++) {
                const int mrow = m0 + wr * 32 + rt * 16 + lg * 4 + q;
                out[(size_t)mrow * DIM + ncol] = acc[rt][ct][q] + bsv;
            }
        }
    }
}

extern "C" void kernel_launch(void* const* d_in, const int* in_sizes, int n_in,
                              void* d_out, int out_size, void* d_ws, size_t ws_size,
                              hipStream_t stream) {
    (void)in_sizes; (void)n_in; (void)out_size; (void)ws_size;
    const float* x  = (const float*)d_in[0];
    const float* Wq = (const float*)d_in[1];
    const float* bq = (const float*)d_in[2];
    const float* Wk = (const float*)d_in[3];
    const float* bk = (const float*)d_in[4];
    const float* Wv = (const float*)d_in[5];
    const float* bv = (const float*)d_in[6];
    const float* Wo = (const float*)d_in[7];
    const float* bo = (const float*)d_in[8];
    float* out = (float*)d_out;
    char* ws = (char*)d_ws;

    unsigned short* xb  = (unsigned short*)(ws);              //  8 MB
    unsigned short* qbf = (unsigned short*)(ws + 8388608);    //  8 MB
    unsigned short* kbf = (unsigned short*)(ws + 16777216);   //  2 MB
    unsigned short* ctx = (unsigned short*)(ws + 20971520);   //  8 MB
    unsigned short* wqt = (unsigned short*)(ws + 29360128);   //  2 MB
    unsigned short* wkt = (unsigned short*)(ws + 31457280);   // .5 MB
    unsigned short* wvt = (unsigned short*)(ws + 31981568);   // .5 MB
    unsigned short* wot = (unsigned short*)(ws + 32505856);   //  2 MB
    float* cosb = (float*)(ws + 34603008);                    // .25 MB
    float* sinb = (float*)(ws + 34865152);                    // .25 MB
    unsigned short* vTb = (unsigned short*)(ws + 35127296);   //  4 MB  [8][64][2048]

    hipLaunchKernelGGL(prep_kernel, dim3(3328), dim3(256), 0, stream,
                       x, Wq, Wk, Wv, Wo, xb, wqt, wkt, wvt, wot, cosb, sinb);
    hipLaunchKernelGGL(qkv_gemm_kernel, dim3(768), dim3(256), 0, stream,
                       xb, wqt, wkt, wvt, bq, bk, bv, cosb, sinb, qbf, kbf, vTb);
    hipLaunchKernelGGL(attn_mfma_kernel, dim3(32, NH, NB), dim3(128), 0, stream,
                       qbf, kbf, vTb, ctx);
    hipLaunchKernelGGL(outproj_kernel, dim3(512), dim3(256), 0, stream,
                       ctx, wot, bo, out);
}

// Round 11
// 102.244 us; speedup vs baseline: 1.1419x; 1.1419x over previous
//
#include <hip/hip_runtime.h>
#include <math.h>

#define DIM 1024
#define NH 16
#define NKV 4
#define HD 64
#define HALF 32
#define NB 2
#define SEQ 2048
#define KVD 256         // NKV*HD
#define MTOT 4096       // NB*SEQ
#define QSCALE 0.18033688f   // 0.125 * log2(e): softmax runs in exp2 domain
#define MBIAS 8.0f           // static softmax bias (S sd ~0.6; overflow-safe by >100 binades)

typedef __bf16 bf16x8 __attribute__((ext_vector_type(8)));
typedef float f32x4 __attribute__((ext_vector_type(4)));
typedef unsigned short u16x8 __attribute__((ext_vector_type(8)));

#define MFMA16(a, b, c) __builtin_amdgcn_mfma_f32_16x16x32_bf16(a, b, c, 0, 0, 0)

__device__ __forceinline__ unsigned short f2bf(float f) {
    unsigned int u = __float_as_uint(f);
    u = (u + 0x7fffu + ((u >> 16) & 1u)) >> 16;
    return (unsigned short)u;
}

// packed f32x2 -> bf16x2 (RNE), single HW instruction
__device__ __forceinline__ unsigned cvt_pk(float lo, float hi) {
    unsigned r;
    asm("v_cvt_pk_bf16_f32 %0, %1, %2" : "=v"(r) : "v"(lo), "v"(hi));
    return r;
}

// async 16B global->LDS: LDS dest = wave-uniform base + lane*16
__device__ __forceinline__ void gll16(const unsigned short* g, unsigned short* l) {
    __builtin_amdgcn_global_load_lds((const __attribute__((address_space(1))) void*)g,
                                     (__attribute__((address_space(3))) void*)l, 16, 0, 0);
}

// ---------------- merged prep: rope table + x->bf16 + weight transpose ----------------
__global__ __launch_bounds__(256) void prep_kernel(
    const float* __restrict__ x,
    const float* __restrict__ Wq, const float* __restrict__ Wk,
    const float* __restrict__ Wv, const float* __restrict__ Wo,
    unsigned short* __restrict__ xb,
    unsigned short* __restrict__ qt, unsigned short* __restrict__ kt,
    unsigned short* __restrict__ vt, unsigned short* __restrict__ ot,
    float* __restrict__ cosb, float* __restrict__ sinb)
{
    __shared__ float tile[64][65];
    const int bx = blockIdx.x;
    const int tid = threadIdx.x;
    if (bx < 256) {
        int idx = bx * 256 + tid;         // 64K entries
        int t = idx >> 5, d = idx & 31;
        float e = (float)(2 * d) / (float)HD;
        float invf = 1.0f / powf(10000.0f, e);
        float f = (float)t * invf;
        cosb[idx] = cosf(f);
        sinb[idx] = sinf(f);
    } else if (bx < 2304) {
        int i = ((bx - 256) * 256 + tid) * 8;
        float4 v0 = *(const float4*)&x[i];
        float4 v1 = *(const float4*)&x[i + 4];
        u16x8 o;
        o[0] = f2bf(v0.x); o[1] = f2bf(v0.y); o[2] = f2bf(v0.z); o[3] = f2bf(v0.w);
        o[4] = f2bf(v1.x); o[5] = f2bf(v1.y); o[6] = f2bf(v1.z); o[7] = f2bf(v1.w);
        *(u16x8*)&xb[i] = o;
    } else {
        int idx2 = bx - 2304;             // 1024 blocks: 4 matrices x 16x16 tiles
        int z = idx2 >> 8, rem = idx2 & 255, xx = rem & 15, yy = rem >> 4;
        const float* W; unsigned short* Wt; int N;
        switch (z) {
            case 0: W = Wq; Wt = qt; N = DIM; break;
            case 1: W = Wk; Wt = kt; N = KVD; break;
            case 2: W = Wv; Wt = vt; N = KVD; break;
            default: W = Wo; Wt = ot; N = DIM; break;
        }
        const int n0 = xx * 64;
        if (n0 >= N) return;
        const int k0 = yy * 64;
        const int row = tid >> 2, coff = (tid & 3) * 16;
#pragma unroll
        for (int i = 0; i < 4; i++) {
            float4 v = *(const float4*)&W[(size_t)(k0 + row) * N + n0 + coff + i * 4];
            tile[row][coff + i * 4 + 0] = v.x; tile[row][coff + i * 4 + 1] = v.y;
            tile[row][coff + i * 4 + 2] = v.z; tile[row][coff + i * 4 + 3] = v.w;
        }
        __syncthreads();
        u16x8 a, b;
#pragma unroll
        for (int i = 0; i < 8; i++) a[i] = f2bf(tile[coff + i][row]);
#pragma unroll
        for (int i = 0; i < 8; i++) b[i] = f2bf(tile[coff + 8 + i][row]);
        *(u16x8*)&Wt[(size_t)(n0 + row) * DIM + k0 + coff] = a;
        *(u16x8*)&Wt[(size_t)(n0 + row) * DIM + k0 + coff + 8] = b;
    }
}

// ---------------- fused QKV GEMM + bias + RoPE; V written transposed ----------------
// 64x128 tile (M x N), 4 waves 2x2 (wave tile 32x64); 768 blocks = 3/CU
__global__ __launch_bounds__(256) void qkv_gemm_kernel(
    const unsigned short* __restrict__ xb,
    const unsigned short* __restrict__ wqt, const unsigned short* __restrict__ wkt,
    const unsigned short* __restrict__ wvt,
    const float* __restrict__ bq, const float* __restrict__ bk, const float* __restrict__ bv,
    const float* __restrict__ cosb, const float* __restrict__ sinb,
    unsigned short* __restrict__ qbuf, unsigned short* __restrict__ kbuf,
    unsigned short* __restrict__ vT)
{
    __shared__ unsigned short As[64 * 32];
    __shared__ unsigned short Bs[128 * 32];
    const int tid = threadIdx.x;
    const int lane = tid & 63, w = tid >> 6;
    const int l15 = lane & 15, lg = lane >> 4;
    const int bid = blockIdx.x;                 // 768 blocks
    const int lid = (bid & 7) * 96 + (bid >> 3);
    const int m0 = (lid / 12) * 64;
    const int n0g = (lid % 12) * 128;

    const unsigned short* Wt; const float* bias; int n0, mode;
    if (n0g < DIM)            { Wt = wqt; bias = bq; n0 = n0g; mode = 0; }
    else if (n0g < DIM + KVD) { Wt = wkt; bias = bk; n0 = n0g - DIM; mode = 1; }
    else                      { Wt = wvt; bias = bv; n0 = n0g - DIM - KVD; mode = 2; }

    const int wr = w >> 1, wc = w & 1;          // wave tile 32x64 at (wr*32, wc*64)
    const int Ar = tid >> 2, Ac8 = (tid & 3) * 8;

    f32x4 acc[2][4];
#pragma unroll
    for (int i = 0; i < 2; i++)
#pragma unroll
        for (int j = 0; j < 4; j++) acc[i][j] = (f32x4){0.f, 0.f, 0.f, 0.f};

    for (int k0 = 0; k0 < DIM; k0 += 32) {
        __syncthreads();
        gll16(xb + (size_t)(m0 + Ar) * DIM + k0 + Ac8, &As[(tid & ~63) * 8]);
#pragma unroll
        for (int i = 0; i < 2; i++) {
            int S = i * 256 + tid;
            int r = S >> 2, c8 = (S & 3) * 8;
            gll16(Wt + (size_t)(n0 + r) * DIM + k0 + c8, &Bs[(i * 256 + (tid & ~63)) * 8]);
        }
        __syncthreads();
        bf16x8 af[2], bfr[4];
#pragma unroll
        for (int r = 0; r < 2; r++)
            af[r] = *(const bf16x8*)&As[(wr * 32 + r * 16 + l15) * 32 + lg * 8];
#pragma unroll
        for (int c = 0; c < 4; c++)
            bfr[c] = *(const bf16x8*)&Bs[(wc * 64 + c * 16 + l15) * 32 + lg * 8];
#pragma unroll
        for (int r = 0; r < 2; r++)
#pragma unroll
            for (int c = 0; c < 4; c++)
                acc[r][c] = MFMA16(af[r], bfr[c], acc[r][c]);
    }

    const int nloc = n0 + wc * 64;
    const bool even = (l15 & 1) == 0;
#pragma unroll
    for (int rt = 0; rt < 2; rt++) {
#pragma unroll
        for (int ct = 0; ct < 4; ct++) {
            const int c = ct * 16 + l15;
            const float bsv = bias[nloc + c];
            if (mode == 2) {
                const int col = nloc + c;               // 0..255
                const int khh = col >> 6, d = col & 63;
                const int bb = m0 >> 11;
                const int t = (m0 & (SEQ - 1)) + wr * 32 + rt * 16 + lg * 4;
                float v0 = acc[rt][ct][0] + bsv;
                float v1 = acc[rt][ct][1] + bsv;
                float v2 = acc[rt][ct][2] + bsv;
                float v3 = acc[rt][ct][3] + bsv;
                unsigned short* dst = vT + ((size_t)(bb * NKV + khh) * 64 + d) * SEQ + t;
                *(uint2*)dst = make_uint2(cvt_pk(v0, v1), cvt_pk(v2, v3));
            } else {
                const int p = c >> 1;
#pragma unroll
                for (int q = 0; q < 4; q++) {
                    const int mrow = m0 + wr * 32 + rt * 16 + lg * 4 + q;
                    float val = acc[rt][ct][q] + bsv;
                    float prt = __shfl_xor(val, 1);
                    const int t = mrow & (SEQ - 1);
                    float cs = cosb[t * HALF + p];
                    float sn = sinb[t * HALF + p];
                    float outv = even ? (val * cs - prt * sn) : (prt * sn - val * cs);
                    int outc = even ? p : (p + 32);
                    if (mode == 0) qbuf[(size_t)mrow * DIM + nloc + outc] = f2bf(outv * QSCALE);
                    else           kbuf[(size_t)mrow * KVD + nloc + outc] = f2bf(outv);
                }
            }
        }
    }
}

// ---------------- flash attention: R9 structure + balanced-sum tile mapping ----------------
// softmax: STATIC bias P = exp2(S - 8); ratios exact, overflow-safe
__global__ __launch_bounds__(256, 4) void attn_mfma_kernel(
    const unsigned short* __restrict__ qb, const unsigned short* __restrict__ kb,
    const unsigned short* __restrict__ vT, unsigned short* __restrict__ ctx)
{
    __shared__ unsigned short Ks[2][64 * 64];   // [key][d], XOR-swizzled, double-buffered
    __shared__ unsigned short Vt[2][64 * 64];   // [d][j], j swizzled by (d&7)<<3
    __shared__ unsigned Pw[4][16 * 32];         // per-wave P rows  (total LDS = 40 KB)

    const int tid = threadIdx.x;
    const int lane = tid & 63, w = tid >> 6;
    const int l15 = lane & 15, lg = lane >> 4;
    const int h = blockIdx.y;
    const int b = blockIdx.z;
    const int kh = h >> 2;
    // balanced tile mapping: a CU's 4 blocks share x, g differs by 8 -> orbit {v,v+8,v+16,v+24}.
    // Map orbit to {r, r+8, 31-r, 23-r}: per-CU chunk totals = 66 exactly (bijective per (h,b)).
    const int g = h + NH * b;                   // 0..31
    const int v = (blockIdx.x + g) & 31;
    const int r_ = v & 7, k_ = v >> 3;
    const int tile = (k_ == 0) ? r_ : (k_ == 1) ? (r_ + 8) : (k_ == 2) ? (31 - r_) : (23 - r_);
    const int q0 = tile * 64;

    const unsigned short* kg = kb + (size_t)b * SEQ * KVD + (size_t)kh * HD;
    const unsigned short* vg = vT + ((size_t)(b * NKV + kh) * HD) * SEQ;

    const int qg_row = w * 16 + l15;
    const int swzd = (l15 & 7) << 3;
    unsigned* PW = &Pw[w][l15 * 32];
    const int pswz = (l15 & 7) << 2;

    // ---- Q fragments direct from global (once per block; chunk loop amortizes) ----
    const unsigned short* qptr = qb + ((size_t)(b * SEQ + q0 + qg_row) * DIM + h * HD + lg * 8);
    bf16x8 bq0 = *(const bf16x8*)qptr;
    bf16x8 bq1 = *(const bf16x8*)(qptr + 32);

    // staging geometry (per wave): slot S -> row r = S>>3, 16B quad qd = S&7
    const int S1 = w * 64 + lane, r1 = S1 >> 3, d81 = ((S1 & 7) ^ (r1 & 7)) * 8;
    const int S2 = 256 + w * 64 + lane, r2 = S2 >> 3, d82 = ((S2 & 7) ^ (r2 & 7)) * 8;

    // ---- prologue: stage K/V chunk 0 into buf 0 ----
    gll16(kg + (size_t)r1 * KVD + d81, &Ks[0][(w * 64) * 8]);
    gll16(vg + (size_t)r1 * SEQ + d81, &Vt[0][(w * 64) * 8]);
    gll16(kg + (size_t)r2 * KVD + d82, &Ks[0][(256 + w * 64) * 8]);
    gll16(vg + (size_t)r2 * SEQ + d82, &Vt[0][(256 + w * 64) * 8]);
    __syncthreads();

    f32x4 o[4];
#pragma unroll
    for (int i = 0; i < 4; i++) o[i] = (f32x4){0.f, 0.f, 0.f, 0.f};
    float lrun = 0.f;   // per-lane partial row-sum; reduced once in epilogue

    const int nch = tile + 1;
#pragma unroll 1
    for (int ch = 0; ch < nch; ch++) {
        const int cur = ch & 1;
        // ---- issue next chunk's staging early (hidden under compute) ----
        if (ch + 1 < nch) {
            const int kv1 = (ch + 1) * 64;
            gll16(kg + (size_t)(kv1 + r1) * KVD + d81, &Ks[cur ^ 1][(w * 64) * 8]);
            gll16(vg + (size_t)r1 * SEQ + kv1 + d81,   &Vt[cur ^ 1][(w * 64) * 8]);
            gll16(kg + (size_t)(kv1 + r2) * KVD + d82, &Ks[cur ^ 1][(256 + w * 64) * 8]);
            gll16(vg + (size_t)r2 * SEQ + kv1 + d82,   &Vt[cur ^ 1][(256 + w * 64) * 8]);
        }

        // ---- S^T = K Q^T : lane holds S[q=l15][key = ct*16 + lg*4 + reg] ----
        f32x4 sacc[4];
#pragma unroll
        for (int i = 0; i < 4; i++) sacc[i] = (f32x4){0.f, 0.f, 0.f, 0.f};
        __builtin_amdgcn_s_setprio(1);
#pragma unroll
        for (int ct = 0; ct < 4; ct++) {
            const int kr = ct * 16 + l15;
            bf16x8 ak = *(const bf16x8*)&Ks[cur][kr * 64 + ((lg * 8) ^ swzd)];
            sacc[ct] = MFMA16(ak, bq0, sacc[ct]);
        }
#pragma unroll
        for (int ct = 0; ct < 4; ct++) {
            const int kr = ct * 16 + l15;
            bf16x8 ak = *(const bf16x8*)&Ks[cur][kr * 64 + ((32 + lg * 8) ^ swzd)];
            sacc[ct] = MFMA16(ak, bq1, sacc[ct]);
        }
        __builtin_amdgcn_s_setprio(0);

        // ---- causal mask (diagonal tile only) ----
        if (ch == nch - 1) {
#pragma unroll
            for (int ct = 0; ct < 4; ct++)
#pragma unroll
                for (int r = 0; r < 4; r++)
                    if (ct * 16 + lg * 4 + r > qg_row) sacc[ct][r] = -INFINITY;
        }

        // ---- P = exp2(S - MBIAS), accumulate per-lane row-sum, pack ----
        float rs = 0.f;
        unsigned pk0[4], pk1[4];
#pragma unroll
        for (int ct = 0; ct < 4; ct++) {
            float p0 = exp2f(sacc[ct][0] - MBIAS);
            float p1 = exp2f(sacc[ct][1] - MBIAS);
            float p2 = exp2f(sacc[ct][2] - MBIAS);
            float p3 = exp2f(sacc[ct][3] - MBIAS);
            rs += (p0 + p1) + (p2 + p3);
            pk0[ct] = cvt_pk(p0, p1);
            pk1[ct] = cvt_pk(p2, p3);
        }
        lrun += rs;

        // ---- P rows -> per-wave LDS (packed b64, swizzled) ----
#pragma unroll
        for (int ct = 0; ct < 4; ct++) {
            int wrd = (ct * 8 + lg * 2) ^ pswz;
            *(uint2*)&PW[wrd] = make_uint2(pk0[ct], pk1[ct]);
        }

        // ---- O += P V ----
        __builtin_amdgcn_s_setprio(1);
#pragma unroll
        for (int s = 0; s < 2; s++) {
            int wrd = (s * 16 + lg * 4) ^ pswz;
            bf16x8 ap = *(const bf16x8*)&PW[wrd];
#pragma unroll
            for (int dt = 0; dt < 4; dt++) {
                const int d = dt * 16 + l15;
                bf16x8 bv2 = *(const bf16x8*)&Vt[cur][d * 64 + ((s * 32 + lg * 8) ^ ((d & 7) << 3))];
                o[dt] = MFMA16(ap, bv2, o[dt]);
            }
        }
        __builtin_amdgcn_s_setprio(0);

        __syncthreads();   // drains staging loads; protects buffer swap
    }

    // ---- epilogue: reduce row-sum, normalize, write ctx ----
    lrun += __shfl_xor(lrun, 16);
    lrun += __shfl_xor(lrun, 32);
    float linv = 1.0f / lrun;
    float lb0 = __shfl(linv, lg * 4 + 0);
    float lb1 = __shfl(linv, lg * 4 + 1);
    float lb2 = __shfl(linv, lg * 4 + 2);
    float lb3 = __shfl(linv, lg * 4 + 3);
#pragma unroll
    for (int dt = 0; dt < 4; dt++) {
        const size_t base = (size_t)(b * SEQ + q0 + w * 16 + lg * 4) * DIM + h * HD + dt * 16 + l15;
        ctx[base]           = f2bf(o[dt][0] * lb0);
        ctx[base + DIM]     = f2bf(o[dt][1] * lb1);
        ctx[base + 2 * DIM] = f2bf(o[dt][2] * lb2);
        ctx[base + 3 * DIM] = f2bf(o[dt][3] * lb3);
    }
}

// ---------------- out projection: 64x128 tile, 512 blocks = 2/CU ----------------
__global__ __launch_bounds__(256) void outproj_kernel(
    const unsigned short* __restrict__ ctx, const unsigned short* __restrict__ wot,
    const float* __restrict__ bo, float* __restrict__ out)
{
    __shared__ unsigned short As[64 * 32];
    __shared__ unsigned short Bs[128 * 32];
    const int tid = threadIdx.x;
    const int lane = tid & 63, w = tid >> 6;
    const int l15 = lane & 15, lg = lane >> 4;
    const int bid = blockIdx.x;                 // 512 blocks
    const int lid = (bid & 7) * 64 + (bid >> 3);
    const int m0 = (lid >> 3) * 64;
    const int n0 = (lid & 7) * 128;
    const int wr = w >> 1, wc = w & 1;
    const int Ar = tid >> 2, Ac8 = (tid & 3) * 8;

    f32x4 acc[2][4];
#pragma unroll
    for (int i = 0; i < 2; i++)
#pragma unroll
        for (int j = 0; j < 4; j++) acc[i][j] = (f32x4){0.f, 0.f, 0.f, 0.f};

    for (int k0 = 0; k0 < DIM; k0 += 32) {
        __syncthreads();
        gll16(ctx + (size_t)(m0 + Ar) * DIM + k0 + Ac8, &As[(tid & ~63) * 8]);
#pragma unroll
        for (int i = 0; i < 2; i++) {
            int S = i * 256 + tid;
            int r = S >> 2, c8 = (S & 3) * 8;
            gll16(wot + (size_t)(n0 + r) * DIM + k0 + c8, &Bs[(i * 256 + (tid & ~63)) * 8]);
        }
        __syncthreads();
        bf16x8 af[2], bfr[4];
#pragma unroll
        for (int r = 0; r < 2; r++)
            af[r] = *(const bf16x8*)&As[(wr * 32 + r * 16 + l15) * 32 + lg * 8];
#pragma unroll
        for (int c = 0; c < 4; c++)
            bfr[c] = *(const bf16x8*)&Bs[(wc * 64 + c * 16 + l15) * 32 + lg * 8];
#pragma unroll
        for (int r = 0; r < 2; r++)
#pragma unroll
            for (int c = 0; c < 4; c++)
                acc[r][c] = MFMA16(af[r], bfr[c], acc[r][c]);
    }

#pragma unroll
    for (int rt = 0; rt < 2; rt++) {
#pragma unroll
        for (int ct = 0; ct < 4; ct++) {
            const int ncol = n0 + wc * 64 + ct * 16 + l15;
            const float bsv = bo[ncol];
#pragma unroll
            for (int q = 0; q < 4; q++) {
                const int mrow = m0 + wr * 32 + rt * 16 + lg * 4 + q;
                out[(size_t)mrow * DIM + ncol] = acc[rt][ct][q] + bsv;
            }
        }
    }
}

extern "C" void kernel_launch(void* const* d_in, const int* in_sizes, int n_in,
                              void* d_out, int out_size, void* d_ws, size_t ws_size,
                              hipStream_t stream) {
    (void)in_sizes; (void)n_in; (void)out_size; (void)ws_size;
    const float* x  = (const float*)d_in[0];
    const float* Wq = (const float*)d_in[1];
    const float* bq = (const float*)d_in[2];
    const float* Wk = (const float*)d_in[3];
    const float* bk = (const float*)d_in[4];
    const float* Wv = (const float*)d_in[5];
    const float* bv = (const float*)d_in[6];
    const float* Wo = (const float*)d_in[7];
    const float* bo = (const float*)d_in[8];
    float* out = (float*)d_out;
    char* ws = (char*)d_ws;

    unsigned short* xb  = (unsigned short*)(ws);              //  8 MB
    unsigned short* qbf = (unsigned short*)(ws + 8388608);    //  8 MB
    unsigned short* kbf = (unsigned short*)(ws + 16777216);   //  2 MB
    unsigned short* ctx = (unsigned short*)(ws + 20971520);   //  8 MB
    unsigned short* wqt = (unsigned short*)(ws + 29360128);   //  2 MB
    unsigned short* wkt = (unsigned short*)(ws + 31457280);   // .5 MB
    unsigned short* wvt = (unsigned short*)(ws + 31981568);   // .5 MB
    unsigned short* wot = (unsigned short*)(ws + 32505856);   //  2 MB
    float* cosb = (float*)(ws + 34603008);                    // .25 MB
    float* sinb = (float*)(ws + 34865152);                    // .25 MB
    unsigned short* vTb = (unsigned short*)(ws + 35127296);   //  4 MB  [8][64][2048]

    hipLaunchKernelGGL(prep_kernel, dim3(3328), dim3(256), 0, stream,
                       x, Wq, Wk, Wv, Wo, xb, wqt, wkt, wvt, wot, cosb, sinb);
    hipLaunchKernelGGL(qkv_gemm_kernel, dim3(768), dim3(256), 0, stream,
                       xb, wqt, wkt, wvt, bq, bk, bv, cosb, sinb, qbf, kbf, vTb);
    hipLaunchKernelGGL(attn_mfma_kernel, dim3(32, NH, NB), dim3(256), 0, stream,
                       qbf, kbf, vTb, ctx);
    hipLaunchKernelGGL(outproj_kernel, dim3(512), dim3(256), 0, stream,
                       ctx, wot, bo, out);
}

// Round 12
// 92.231 us; speedup vs baseline: 1.2659x; 1.1086x over previous
//
#include <hip/hip_runtime.h>
#include <math.h>

#define DIM 1024
#define NH 16
#define NKV 4
#define HD 64
#define HALF 32
#define NB 2
#define SEQ 2048
#define KVD 256         // NKV*HD
#define MTOT 4096       // NB*SEQ
#define QSCALE 0.18033688f   // 0.125 * log2(e): softmax runs in exp2 domain
#define MBIAS 8.0f           // static softmax bias (S sd ~0.6; overflow-safe by >100 binades)

typedef __bf16 bf16x8 __attribute__((ext_vector_type(8)));
typedef float f32x4 __attribute__((ext_vector_type(4)));
typedef unsigned short u16x8 __attribute__((ext_vector_type(8)));

#define MFMA16(a, b, c) __builtin_amdgcn_mfma_f32_16x16x32_bf16(a, b, c, 0, 0, 0)

__device__ __forceinline__ unsigned short f2bf(float f) {
    unsigned int u = __float_as_uint(f);
    u = (u + 0x7fffu + ((u >> 16) & 1u)) >> 16;
    return (unsigned short)u;
}

// packed f32x2 -> bf16x2 (RNE), single HW instruction
__device__ __forceinline__ unsigned cvt_pk(float lo, float hi) {
    unsigned r;
    asm("v_cvt_pk_bf16_f32 %0, %1, %2" : "=v"(r) : "v"(lo), "v"(hi));
    return r;
}

// async 16B global->LDS: LDS dest = wave-uniform base + lane*16
__device__ __forceinline__ void gll16(const unsigned short* g, unsigned short* l) {
    __builtin_amdgcn_global_load_lds((const __attribute__((address_space(1))) void*)g,
                                     (__attribute__((address_space(3))) void*)l, 16, 0, 0);
}

// ---------------- merged prep: rope table + x->bf16 + weight transpose ----------------
__global__ __launch_bounds__(256) void prep_kernel(
    const float* __restrict__ x,
    const float* __restrict__ Wq, const float* __restrict__ Wk,
    const float* __restrict__ Wv, const float* __restrict__ Wo,
    unsigned short* __restrict__ xb,
    unsigned short* __restrict__ qt, unsigned short* __restrict__ kt,
    unsigned short* __restrict__ vt, unsigned short* __restrict__ ot,
    float* __restrict__ cosb, float* __restrict__ sinb)
{
    __shared__ float tile[64][65];
    const int bx = blockIdx.x;
    const int tid = threadIdx.x;
    if (bx < 256) {
        int idx = bx * 256 + tid;         // 64K entries
        int t = idx >> 5, d = idx & 31;
        float e = (float)(2 * d) / (float)HD;
        float invf = 1.0f / powf(10000.0f, e);
        float f = (float)t * invf;
        cosb[idx] = cosf(f);
        sinb[idx] = sinf(f);
    } else if (bx < 2304) {
        int i = ((bx - 256) * 256 + tid) * 8;
        float4 v0 = *(const float4*)&x[i];
        float4 v1 = *(const float4*)&x[i + 4];
        u16x8 o;
        o[0] = f2bf(v0.x); o[1] = f2bf(v0.y); o[2] = f2bf(v0.z); o[3] = f2bf(v0.w);
        o[4] = f2bf(v1.x); o[5] = f2bf(v1.y); o[6] = f2bf(v1.z); o[7] = f2bf(v1.w);
        *(u16x8*)&xb[i] = o;
    } else {
        int idx2 = bx - 2304;             // 1024 blocks: 4 matrices x 16x16 tiles
        int z = idx2 >> 8, rem = idx2 & 255, xx = rem & 15, yy = rem >> 4;
        const float* W; unsigned short* Wt; int N;
        switch (z) {
            case 0: W = Wq; Wt = qt; N = DIM; break;
            case 1: W = Wk; Wt = kt; N = KVD; break;
            case 2: W = Wv; Wt = vt; N = KVD; break;
            default: W = Wo; Wt = ot; N = DIM; break;
        }
        const int n0 = xx * 64;
        if (n0 >= N) return;
        const int k0 = yy * 64;
        const int row = tid >> 2, coff = (tid & 3) * 16;
#pragma unroll
        for (int i = 0; i < 4; i++) {
            float4 v = *(const float4*)&W[(size_t)(k0 + row) * N + n0 + coff + i * 4];
            tile[row][coff + i * 4 + 0] = v.x; tile[row][coff + i * 4 + 1] = v.y;
            tile[row][coff + i * 4 + 2] = v.z; tile[row][coff + i * 4 + 3] = v.w;
        }
        __syncthreads();
        u16x8 a, b;
#pragma unroll
        for (int i = 0; i < 8; i++) a[i] = f2bf(tile[coff + i][row]);
#pragma unroll
        for (int i = 0; i < 8; i++) b[i] = f2bf(tile[coff + 8 + i][row]);
        *(u16x8*)&Wt[(size_t)(n0 + row) * DIM + k0 + coff] = a;
        *(u16x8*)&Wt[(size_t)(n0 + row) * DIM + k0 + coff + 8] = b;
    }
}

// ---------------- fused QKV GEMM + bias + RoPE; V written transposed ----------------
// 64x128 tile, BK=64 (1 barrier-pair per 16 MFMA/wave); XOR-swizzled LDS (128B rows)
__global__ __launch_bounds__(256) void qkv_gemm_kernel(
    const unsigned short* __restrict__ xb,
    const unsigned short* __restrict__ wqt, const unsigned short* __restrict__ wkt,
    const unsigned short* __restrict__ wvt,
    const float* __restrict__ bq, const float* __restrict__ bk, const float* __restrict__ bv,
    const float* __restrict__ cosb, const float* __restrict__ sinb,
    unsigned short* __restrict__ qbuf, unsigned short* __restrict__ kbuf,
    unsigned short* __restrict__ vT)
{
    __shared__ unsigned short As[64 * 64];    //  8 KB, row-major, quad-swizzled
    __shared__ unsigned short Bs[128 * 64];   // 16 KB
    const int tid = threadIdx.x;
    const int lane = tid & 63, w = tid >> 6;
    const int l15 = lane & 15, lg = lane >> 4;
    const int bid = blockIdx.x;                 // 768 blocks
    const int lid = (bid & 7) * 96 + (bid >> 3);
    const int m0 = (lid / 12) * 64;
    const int n0g = (lid % 12) * 128;

    const unsigned short* Wt; const float* bias; int n0, mode;
    if (n0g < DIM)            { Wt = wqt; bias = bq; n0 = n0g; mode = 0; }
    else if (n0g < DIM + KVD) { Wt = wkt; bias = bk; n0 = n0g - DIM; mode = 1; }
    else                      { Wt = wvt; bias = bv; n0 = n0g - DIM - KVD; mode = 2; }

    const int wr = w >> 1, wc = w & 1;          // wave tile 32x64 at (wr*32, wc*64)

    f32x4 acc[2][4];
#pragma unroll
    for (int i = 0; i < 2; i++)
#pragma unroll
        for (int j = 0; j < 4; j++) acc[i][j] = (f32x4){0.f, 0.f, 0.f, 0.f};

    for (int k0 = 0; k0 < DIM; k0 += 64) {
        __syncthreads();
        // A: 512 slots of 16B (8 slots/row), pre-swizzled global quad
#pragma unroll
        for (int i = 0; i < 2; i++) {
            int S = i * 256 + tid;
            int r = S >> 3, qd = S & 7;
            gll16(xb + (size_t)(m0 + r) * DIM + k0 + ((qd ^ (r & 7)) * 8),
                  &As[(i * 256 + (tid & ~63)) * 8]);
        }
        // B: 1024 slots
#pragma unroll
        for (int i = 0; i < 4; i++) {
            int S = i * 256 + tid;
            int r = S >> 3, qd = S & 7;
            gll16(Wt + (size_t)(n0 + r) * DIM + k0 + ((qd ^ (r & 7)) * 8),
                  &Bs[(i * 256 + (tid & ~63)) * 8]);
        }
        __syncthreads();
        bf16x8 af[2][2], bfr[4][2];
#pragma unroll
        for (int r = 0; r < 2; r++) {
            const int row = wr * 32 + r * 16 + l15;
#pragma unroll
            for (int kk = 0; kk < 2; kk++)
                af[r][kk] = *(const bf16x8*)&As[row * 64 + (((kk * 4 + lg) ^ (row & 7)) << 3)];
        }
#pragma unroll
        for (int c = 0; c < 4; c++) {
            const int row = wc * 64 + c * 16 + l15;
#pragma unroll
            for (int kk = 0; kk < 2; kk++)
                bfr[c][kk] = *(const bf16x8*)&Bs[row * 64 + (((kk * 4 + lg) ^ (row & 7)) << 3)];
        }
#pragma unroll
        for (int kk = 0; kk < 2; kk++)
#pragma unroll
            for (int r = 0; r < 2; r++)
#pragma unroll
                for (int c = 0; c < 4; c++)
                    acc[r][c] = MFMA16(af[r][kk], bfr[c][kk], acc[r][c]);
    }

    const int nloc = n0 + wc * 64;
    const bool even = (l15 & 1) == 0;
#pragma unroll
    for (int rt = 0; rt < 2; rt++) {
#pragma unroll
        for (int ct = 0; ct < 4; ct++) {
            const int c = ct * 16 + l15;
            const float bsv = bias[nloc + c];
            if (mode == 2) {
                const int col = nloc + c;               // 0..255
                const int khh = col >> 6, d = col & 63;
                const int bb = m0 >> 11;
                const int t = (m0 & (SEQ - 1)) + wr * 32 + rt * 16 + lg * 4;
                float v0 = acc[rt][ct][0] + bsv;
                float v1 = acc[rt][ct][1] + bsv;
                float v2 = acc[rt][ct][2] + bsv;
                float v3 = acc[rt][ct][3] + bsv;
                unsigned short* dst = vT + ((size_t)(bb * NKV + khh) * 64 + d) * SEQ + t;
                *(uint2*)dst = make_uint2(cvt_pk(v0, v1), cvt_pk(v2, v3));
            } else {
                const int p = c >> 1;
#pragma unroll
                for (int q = 0; q < 4; q++) {
                    const int mrow = m0 + wr * 32 + rt * 16 + lg * 4 + q;
                    float val = acc[rt][ct][q] + bsv;
                    float prt = __shfl_xor(val, 1);
                    const int t = mrow & (SEQ - 1);
                    float cs = cosb[t * HALF + p];
                    float sn = sinb[t * HALF + p];
                    float outv = even ? (val * cs - prt * sn) : (prt * sn - val * cs);
                    int outc = even ? p : (p + 32);
                    if (mode == 0) qbuf[(size_t)mrow * DIM + nloc + outc] = f2bf(outv * QSCALE);
                    else           kbuf[(size_t)mrow * KVD + nloc + outc] = f2bf(outv);
                }
            }
        }
    }
}

// ---------------- flash attention: R11 structure (balanced-sum tile mapping) ----------------
// softmax: STATIC bias P = exp2(S - 8); ratios exact, overflow-safe
__global__ __launch_bounds__(256, 4) void attn_mfma_kernel(
    const unsigned short* __restrict__ qb, const unsigned short* __restrict__ kb,
    const unsigned short* __restrict__ vT, unsigned short* __restrict__ ctx)
{
    __shared__ unsigned short Ks[2][64 * 64];   // [key][d], XOR-swizzled, double-buffered
    __shared__ unsigned short Vt[2][64 * 64];   // [d][j], j swizzled by (d&7)<<3
    __shared__ unsigned Pw[4][16 * 32];         // per-wave P rows  (total LDS = 40 KB)

    const int tid = threadIdx.x;
    const int lane = tid & 63, w = tid >> 6;
    const int l15 = lane & 15, lg = lane >> 4;
    const int h = blockIdx.y;
    const int b = blockIdx.z;
    const int kh = h >> 2;
    // balanced tile mapping: orbit {v,v+8,v+16,v+24} -> {r, r+8, 31-r, 23-r}: per-CU sum = 66
    const int g = h + NH * b;                   // 0..31
    const int v = (blockIdx.x + g) & 31;
    const int r_ = v & 7, k_ = v >> 3;
    const int tile = (k_ == 0) ? r_ : (k_ == 1) ? (r_ + 8) : (k_ == 2) ? (31 - r_) : (23 - r_);
    const int q0 = tile * 64;

    const unsigned short* kg = kb + (size_t)b * SEQ * KVD + (size_t)kh * HD;
    const unsigned short* vg = vT + ((size_t)(b * NKV + kh) * HD) * SEQ;

    const int qg_row = w * 16 + l15;
    const int swzd = (l15 & 7) << 3;
    unsigned* PW = &Pw[w][l15 * 32];
    const int pswz = (l15 & 7) << 2;

    // ---- Q fragments direct from global (once per block; chunk loop amortizes) ----
    const unsigned short* qptr = qb + ((size_t)(b * SEQ + q0 + qg_row) * DIM + h * HD + lg * 8);
    bf16x8 bq0 = *(const bf16x8*)qptr;
    bf16x8 bq1 = *(const bf16x8*)(qptr + 32);

    // staging geometry (per wave): slot S -> row r = S>>3, 16B quad qd = S&7
    const int S1 = w * 64 + lane, r1 = S1 >> 3, d81 = ((S1 & 7) ^ (r1 & 7)) * 8;
    const int S2 = 256 + w * 64 + lane, r2 = S2 >> 3, d82 = ((S2 & 7) ^ (r2 & 7)) * 8;

    // ---- prologue: stage K/V chunk 0 into buf 0 ----
    gll16(kg + (size_t)r1 * KVD + d81, &Ks[0][(w * 64) * 8]);
    gll16(vg + (size_t)r1 * SEQ + d81, &Vt[0][(w * 64) * 8]);
    gll16(kg + (size_t)r2 * KVD + d82, &Ks[0][(256 + w * 64) * 8]);
    gll16(vg + (size_t)r2 * SEQ + d82, &Vt[0][(256 + w * 64) * 8]);
    __syncthreads();

    f32x4 o[4];
#pragma unroll
    for (int i = 0; i < 4; i++) o[i] = (f32x4){0.f, 0.f, 0.f, 0.f};
    float lrun = 0.f;   // per-lane partial row-sum; reduced once in epilogue

    const int nch = tile + 1;
#pragma unroll 1
    for (int ch = 0; ch < nch; ch++) {
        const int cur = ch & 1;
        // ---- issue next chunk's staging early (hidden under compute) ----
        if (ch + 1 < nch) {
            const int kv1 = (ch + 1) * 64;
            gll16(kg + (size_t)(kv1 + r1) * KVD + d81, &Ks[cur ^ 1][(w * 64) * 8]);
            gll16(vg + (size_t)r1 * SEQ + kv1 + d81,   &Vt[cur ^ 1][(w * 64) * 8]);
            gll16(kg + (size_t)(kv1 + r2) * KVD + d82, &Ks[cur ^ 1][(256 + w * 64) * 8]);
            gll16(vg + (size_t)r2 * SEQ + kv1 + d82,   &Vt[cur ^ 1][(256 + w * 64) * 8]);
        }

        // ---- S^T = K Q^T : lane holds S[q=l15][key = ct*16 + lg*4 + reg] ----
        f32x4 sacc[4];
#pragma unroll
        for (int i = 0; i < 4; i++) sacc[i] = (f32x4){0.f, 0.f, 0.f, 0.f};
        __builtin_amdgcn_s_setprio(1);
#pragma unroll
        for (int ct = 0; ct < 4; ct++) {
            const int kr = ct * 16 + l15;
            bf16x8 ak = *(const bf16x8*)&Ks[cur][kr * 64 + ((lg * 8) ^ swzd)];
            sacc[ct] = MFMA16(ak, bq0, sacc[ct]);
        }
#pragma unroll
        for (int ct = 0; ct < 4; ct++) {
            const int kr = ct * 16 + l15;
            bf16x8 ak = *(const bf16x8*)&Ks[cur][kr * 64 + ((32 + lg * 8) ^ swzd)];
            sacc[ct] = MFMA16(ak, bq1, sacc[ct]);
        }
        __builtin_amdgcn_s_setprio(0);

        // ---- causal mask (diagonal tile only) ----
        if (ch == nch - 1) {
#pragma unroll
            for (int ct = 0; ct < 4; ct++)
#pragma unroll
                for (int r = 0; r < 4; r++)
                    if (ct * 16 + lg * 4 + r > qg_row) sacc[ct][r] = -INFINITY;
        }

        // ---- P = exp2(S - MBIAS), accumulate per-lane row-sum, pack ----
        float rs = 0.f;
        unsigned pk0[4], pk1[4];
#pragma unroll
        for (int ct = 0; ct < 4; ct++) {
            float p0 = exp2f(sacc[ct][0] - MBIAS);
            float p1 = exp2f(sacc[ct][1] - MBIAS);
            float p2 = exp2f(sacc[ct][2] - MBIAS);
            float p3 = exp2f(sacc[ct][3] - MBIAS);
            rs += (p0 + p1) + (p2 + p3);
            pk0[ct] = cvt_pk(p0, p1);
            pk1[ct] = cvt_pk(p2, p3);
        }
        lrun += rs;

        // ---- P rows -> per-wave LDS (packed b64, swizzled) ----
#pragma unroll
        for (int ct = 0; ct < 4; ct++) {
            int wrd = (ct * 8 + lg * 2) ^ pswz;
            *(uint2*)&PW[wrd] = make_uint2(pk0[ct], pk1[ct]);
        }

        // ---- O += P V ----
        __builtin_amdgcn_s_setprio(1);
#pragma unroll
        for (int s = 0; s < 2; s++) {
            int wrd = (s * 16 + lg * 4) ^ pswz;
            bf16x8 ap = *(const bf16x8*)&PW[wrd];
#pragma unroll
            for (int dt = 0; dt < 4; dt++) {
                const int d = dt * 16 + l15;
                bf16x8 bv2 = *(const bf16x8*)&Vt[cur][d * 64 + ((s * 32 + lg * 8) ^ ((d & 7) << 3))];
                o[dt] = MFMA16(ap, bv2, o[dt]);
            }
        }
        __builtin_amdgcn_s_setprio(0);

        __syncthreads();   // drains staging loads; protects buffer swap
    }

    // ---- epilogue: reduce row-sum, normalize, write ctx ----
    lrun += __shfl_xor(lrun, 16);
    lrun += __shfl_xor(lrun, 32);
    float linv = 1.0f / lrun;
    float lb0 = __shfl(linv, lg * 4 + 0);
    float lb1 = __shfl(linv, lg * 4 + 1);
    float lb2 = __shfl(linv, lg * 4 + 2);
    float lb3 = __shfl(linv, lg * 4 + 3);
#pragma unroll
    for (int dt = 0; dt < 4; dt++) {
        const size_t base = (size_t)(b * SEQ + q0 + w * 16 + lg * 4) * DIM + h * HD + dt * 16 + l15;
        ctx[base]           = f2bf(o[dt][0] * lb0);
        ctx[base + DIM]     = f2bf(o[dt][1] * lb1);
        ctx[base + 2 * DIM] = f2bf(o[dt][2] * lb2);
        ctx[base + 3 * DIM] = f2bf(o[dt][3] * lb3);
    }
}

// ---------------- out projection: 64x128 tile, BK=64, XOR-swizzled LDS ----------------
__global__ __launch_bounds__(256) void outproj_kernel(
    const unsigned short* __restrict__ ctx, const unsigned short* __restrict__ wot,
    const float* __restrict__ bo, float* __restrict__ out)
{
    __shared__ unsigned short As[64 * 64];
    __shared__ unsigned short Bs[128 * 64];
    const int tid = threadIdx.x;
    const int lane = tid & 63, w = tid >> 6;
    const int l15 = lane & 15, lg = lane >> 4;
    const int bid = blockIdx.x;                 // 512 blocks
    const int lid = (bid & 7) * 64 + (bid >> 3);
    const int m0 = (lid >> 3) * 64;
    const int n0 = (lid & 7) * 128;
    const int wr = w >> 1, wc = w & 1;

    f32x4 acc[2][4];
#pragma unroll
    for (int i = 0; i < 2; i++)
#pragma unroll
        for (int j = 0; j < 4; j++) acc[i][j] = (f32x4){0.f, 0.f, 0.f, 0.f};

    for (int k0 = 0; k0 < DIM; k0 += 64) {
        __syncthreads();
#pragma unroll
        for (int i = 0; i < 2; i++) {
            int S = i * 256 + tid;
            int r = S >> 3, qd = S & 7;
            gll16(ctx + (size_t)(m0 + r) * DIM + k0 + ((qd ^ (r & 7)) * 8),
                  &As[(i * 256 + (tid & ~63)) * 8]);
        }
#pragma unroll
        for (int i = 0; i < 4; i++) {
            int S = i * 256 + tid;
            int r = S >> 3, qd = S & 7;
            gll16(wot + (size_t)(n0 + r) * DIM + k0 + ((qd ^ (r & 7)) * 8),
                  &Bs[(i * 256 + (tid & ~63)) * 8]);
        }
        __syncthreads();
        bf16x8 af[2][2], bfr[4][2];
#pragma unroll
        for (int r = 0; r < 2; r++) {
            const int row = wr * 32 + r * 16 + l15;
#pragma unroll
            for (int kk = 0; kk < 2; kk++)
                af[r][kk] = *(const bf16x8*)&As[row * 64 + (((kk * 4 + lg) ^ (row & 7)) << 3)];
        }
#pragma unroll
        for (int c = 0; c < 4; c++) {
            const int row = wc * 64 + c * 16 + l15;
#pragma unroll
            for (int kk = 0; kk < 2; kk++)
                bfr[c][kk] = *(const bf16x8*)&Bs[row * 64 + (((kk * 4 + lg) ^ (row & 7)) << 3)];
        }
#pragma unroll
        for (int kk = 0; kk < 2; kk++)
#pragma unroll
            for (int r = 0; r < 2; r++)
#pragma unroll
                for (int c = 0; c < 4; c++)
                    acc[r][c] = MFMA16(af[r][kk], bfr[c][kk], acc[r][c]);
    }

#pragma unroll
    for (int rt = 0; rt < 2; rt++) {
#pragma unroll
        for (int ct = 0; ct < 4; ct++) {
            const int ncol = n0 + wc * 64 + ct * 16 + l15;
            const float bsv = bo[ncol];
#pragma unroll
            for (int q = 0; q < 4; q++) {
                const int mrow = m0 + wr * 32 + rt * 16 + lg * 4 + q;
                out[(size_t)mrow * DIM + ncol] = acc[rt][ct][q] + bsv;
            }
        }
    }
}

extern "C" void kernel_launch(void* const* d_in, const int* in_sizes, int n_in,
                              void* d_out, int out_size, void* d_ws, size_t ws_size,
                              hipStream_t stream) {
    (void)in_sizes; (void)n_in; (void)out_size; (void)ws_size;
    const float* x  = (const float*)d_in[0];
    const float* Wq = (const float*)d_in[1];
    const float* bq = (const float*)d_in[2];
    const float* Wk = (const float*)d_in[3];
    const float* bk = (const float*)d_in[4];
    const float* Wv = (const float*)d_in[5];
    const float* bv = (const float*)d_in[6];
    const float* Wo = (const float*)d_in[7];
    const float* bo = (const float*)d_in[8];
    float* out = (float*)d_out;
    char* ws = (char*)d_ws;

    unsigned short* xb  = (unsigned short*)(ws);              //  8 MB
    unsigned short* qbf = (unsigned short*)(ws + 8388608);    //  8 MB
    unsigned short* kbf = (unsigned short*)(ws + 16777216);   //  2 MB
    unsigned short* ctx = (unsigned short*)(ws + 20971520);   //  8 MB
    unsigned short* wqt = (unsigned short*)(ws + 29360128);   //  2 MB
    unsigned short* wkt = (unsigned short*)(ws + 31457280);   // .5 MB
    unsigned short* wvt = (unsigned short*)(ws + 31981568);   // .5 MB
    unsigned short* wot = (unsigned short*)(ws + 32505856);   //  2 MB
    float* cosb = (float*)(ws + 34603008);                    // .25 MB
    float* sinb = (float*)(ws + 34865152);                    // .25 MB
    unsigned short* vTb = (unsigned short*)(ws + 35127296);   //  4 MB  [8][64][2048]

    hipLaunchKernelGGL(prep_kernel, dim3(3328), dim3(256), 0, stream,
                       x, Wq, Wk, Wv, Wo, xb, wqt, wkt, wvt, wot, cosb, sinb);
    hipLaunchKernelGGL(qkv_gemm_kernel, dim3(768), dim3(256), 0, stream,
                       xb, wqt, wkt, wvt, bq, bk, bv, cosb, sinb, qbf, kbf, vTb);
    hipLaunchKernelGGL(attn_mfma_kernel, dim3(32, NH, NB), dim3(256), 0, stream,
                       qbf, kbf, vTb, ctx);
    hipLaunchKernelGGL(outproj_kernel, dim3(512), dim3(256), 0, stream,
                       ctx, wot, bo, out);
}